// Round 4
// baseline (113.871 us; speedup 1.0000x reference)
//
#include <hip/hip_runtime.h>
#include <math.h>

// Perona-Malik (option 2) fused stencil, x:[B,1,H,W] fp32, H=W=1024.
//
//   fx(i,j) = c*(x[i,jp]-x[i,j]),  jp = (j+1<W)? j+1 : W-2
//   fy(i,j) = c*(x[im,j]-x[i,j]),  im = (i>=1)? i-1 : 1
//   cI = exp(-(fx^2+fy^2)/900);  g = fx*cI;  h = fy*cI
//   out(i,j) = c*(g(i,j)-g(i,jm)) + c*(h(i,j)-h(ip,j))
//     jm = (j>=1)? j-1 : 1 ;  ip = (i+1<H)? i+1 : H-2
//
// Rolling-row structure: each block owns an RR-row tile and sweeps down.
// Per iteration: load ONE new row, eval (g,h) once, emit previous row.
// RR=16: reads = (RR+2)/RR = 1.125x output rows.
// Tile swizzle: dispatch->XCD is round-robin on flat block index, so map
// bx -> tile t = (bx%8)*8 + bx/8: XCD k then owns tiles 8k..8k+7 (a
// contiguous 128-row band) and adjacent tiles' halo rows can L2-hit.

#define HH 1024
#define WW 1024
#define RR 16
#define NTILES (HH / RR)   // 64

typedef float vfloat4 __attribute__((ext_vector_type(4)));

__device__ __forceinline__ void gh_eval(float xc, float xr, float xu,
                                        float& g, float& h) {
    const float c = 0.70710678118654752f;   // 1/sqrt(2)
    float fx = c * (xr - xc);
    float fy = c * (xu - xc);
    float cI = __expf(-(fx * fx + fy * fy) * (1.0f / 900.0f));
    g = fx * cI;
    h = fy * cI;
}

__device__ __forceinline__ void store_nt4(float* p, float a, float b, float cc, float d) {
    vfloat4 v = {a, b, cc, d};
    __builtin_nontemporal_store(v, (vfloat4*)p);
}

__global__ __launch_bounds__(256)
void pm_kernel(const float* __restrict__ x, float* __restrict__ out) {
    const int H = HH, W = WW;
    // XCD-aware tile swizzle (NTILES=64 = 8*8): bx and bx+8 -> adjacent tiles
    const int bx = blockIdx.x;
    const int tile = (bx & 7) * (NTILES / 8) + (bx >> 3);
    const int r0 = tile * RR;             // first output row of this tile
    const int b  = blockIdx.y;
    const float* xb = x + (size_t)b * H * W;
    float*       ob = out + (size_t)b * H * W;
    const int j0 = threadIdx.x << 2;      // 4 pixels/thread
    const int cl = (j0 >= 1)    ? j0 - 1 : 1;      // reflect(j0-1)
    const int cr = (j0 + 4 < W) ? j0 + 4 : W - 2;  // reflect(j0+4)
    const float c = 0.70710678118654752f;

    // ---- prologue: row above (reflected) + first tile row ----
    float xm[5], xr[6];
    {
        const int pm = (r0 >= 1) ? r0 - 1 : 1;     // reflect(r0-1)
        const float4 vm = *(const float4*)(xb + (size_t)pm * W + j0);
        xm[0] = xb[(size_t)pm * W + cl];
        xm[1] = vm.x; xm[2] = vm.y; xm[3] = vm.z; xm[4] = vm.w;

        const float4 vr = *(const float4*)(xb + (size_t)r0 * W + j0);
        xr[0] = xb[(size_t)r0 * W + cl];
        xr[1] = vr.x; xr[2] = vr.y; xr[3] = vr.z; xr[4] = vr.w;
        xr[5] = xb[(size_t)r0 * W + cr];
    }

    // (g,h) for row r0: gw covers cols j0-1..j0+3, hc covers j0..j0+3
    float gw[5], hc[4], hprev[4];
#pragma unroll
    for (int t = 0; t < 5; ++t) {
        float g, h;
        gh_eval(xr[t], xr[t + 1], xm[t], g, h);
        gw[t] = g;
        if (t >= 1) hc[t - 1] = h;
    }
    if (j0 == 0) gw[0] = gw[2];           // jm(0)=1 -> g(i,1)

    // ---- body: rows r0 .. r0+RR-2 always have a next row in-bounds ----
#pragma unroll
    for (int k = 0; k < RR - 1; ++k) {
        const int r = r0 + k;
        // load row r+1 (6-wide window), eval its (g,h) using row r as "up"
        float xn[6];
        {
            const size_t base = (size_t)(r + 1) * W;
            const float4 v = *(const float4*)(xb + base + j0);
            xn[0] = xb[base + cl];
            xn[1] = v.x; xn[2] = v.y; xn[3] = v.z; xn[4] = v.w;
            xn[5] = xb[base + cr];
        }
        float gw2[5], hn[4];
#pragma unroll
        for (int t = 0; t < 5; ++t) {
            float g, h;
            gh_eval(xn[t], xn[t + 1], xr[t], g, h);
            gw2[t] = g;
            if (t >= 1) hn[t - 1] = h;
        }
        if (j0 == 0) gw2[0] = gw2[2];

        store_nt4(ob + (size_t)r * W + j0,
                  c * ((gw[1] - gw[0]) + (hc[0] - hn[0])),
                  c * ((gw[2] - gw[1]) + (hc[1] - hn[1])),
                  c * ((gw[3] - gw[2]) + (hc[2] - hn[2])),
                  c * ((gw[4] - gw[3]) + (hc[3] - hn[3])));

        // shift state down one row
#pragma unroll
        for (int t = 0; t < 6; ++t) xr[t] = xn[t];
#pragma unroll
        for (int t = 0; t < 5; ++t) gw[t] = gw2[t];
#pragma unroll
        for (int t = 0; t < 4; ++t) { hprev[t] = hc[t]; hc[t] = hn[t]; }
    }

    // ---- epilogue row rL = r0+RR-1 ----
    {
        const int rL = r0 + RR - 1;
        float hP[4];
        if (rL + 1 < H) {                  // interior tile: load the halo row
            float xn[6];
            const size_t base = (size_t)(rL + 1) * W;
            const float4 v = *(const float4*)(xb + base + j0);
            xn[0] = xb[base + cl];
            xn[1] = v.x; xn[2] = v.y; xn[3] = v.z; xn[4] = v.w;
            xn[5] = xb[base + cr];
#pragma unroll
            for (int t = 1; t < 5; ++t) {  // only h needed (cols j0..j0+3)
                float g, h;
                gh_eval(xn[t], xn[t + 1], xr[t], g, h);
                hP[t - 1] = h;
            }
        } else {                           // rL = H-1: ip reflects to H-2
            hP[0] = hprev[0]; hP[1] = hprev[1];
            hP[2] = hprev[2]; hP[3] = hprev[3];
        }
        store_nt4(ob + (size_t)rL * W + j0,
                  c * ((gw[1] - gw[0]) + (hc[0] - hP[0])),
                  c * ((gw[2] - gw[1]) + (hc[1] - hP[1])),
                  c * ((gw[3] - gw[2]) + (hc[2] - hP[2])),
                  c * ((gw[4] - gw[3]) + (hc[3] - hP[3])));
    }
}

extern "C" void kernel_launch(void* const* d_in, const int* in_sizes, int n_in,
                              void* d_out, int out_size, void* d_ws, size_t ws_size,
                              hipStream_t stream) {
    const float* x = (const float*)d_in[0];
    float* out = (float*)d_out;
    const int total = in_sizes[0];
    const int B = total / (HH * WW);       // 16
    dim3 grid(NTILES, B);                  // 16-row tile per block
    pm_kernel<<<grid, 256, 0, stream>>>(x, out);
}

// Round 5
// 108.261 us; speedup vs baseline: 1.0518x; 1.0518x over previous
//
#include <hip/hip_runtime.h>
#include <math.h>

// Perona-Malik (option 2) fused stencil, x:[B,1,H,W] fp32, H=W=1024.
//
//   fx(i,j) = c*(x[i,jp]-x[i,j]),  jp = (j+1<W)? j+1 : W-2
//   fy(i,j) = c*(x[im,j]-x[i,j]),  im = (i>=1)? i-1 : 1
//   cI = exp(-(fx^2+fy^2)/900);  g = fx*cI;  h = fy*cI
//   out(i,j) = c*(g(i,j)-g(i,jm)) + c*(h(i,j)-h(ip,j))
//     jm = (j>=1)? j-1 : 1 ;  ip = (i+1<H)? i+1 : H-2
//
// Rolling-row tile (RR=8, proven best in R3). Per iteration: ONE float4 row
// load per thread; halo columns come from neighbor lanes via shuffle
// (ds_permute) instead of two extra scalar L1 loads. Only lanes 0/63 of a
// wave do a real edge load (cross-wave boundary), exec-masked to 2/64 lanes.
// R4 post-mortem: RR=16 + XCD swizzle regressed (I-cache bloat / tail) ->
// reverted to RR=8, no swizzle.

#define HH 1024
#define WW 1024
#define RR 8

typedef float vfloat4 __attribute__((ext_vector_type(4)));

__device__ __forceinline__ void gh_eval(float xc, float xr, float xu,
                                        float& g, float& h) {
    const float c = 0.70710678118654752f;   // 1/sqrt(2)
    float fx = c * (xr - xc);
    float fy = c * (xu - xc);
    float cI = __expf(-(fx * fx + fy * fy) * (1.0f / 900.0f));
    g = fx * cI;
    h = fy * cI;
}

__device__ __forceinline__ void store_nt4(float* p, float a, float b, float cc, float d) {
    vfloat4 v = {a, b, cc, d};
    __builtin_nontemporal_store(v, (vfloat4*)p);
}

// Load a 6-wide window [j0-1 .. j0+4] (with column reflection) using one
// float4 load + lane shuffles; only wave-edge lanes touch memory again.
__device__ __forceinline__ void load_row6(const float* __restrict__ row, int j0,
                                          int lane, float (&xn)[6]) {
    const float4 v = *(const float4*)(row + j0);
    float left  = __shfl_up(v.w, 1);    // lane l-1's col j0-1
    float right = __shfl_down(v.x, 1);  // lane l+1's col j0+4
    if (lane == 0)  left  = (j0 == 0)      ? v.y : row[j0 - 1];   // reflect(−1)=1
    if (lane == 63) right = (j0 + 4 == WW) ? v.z : row[j0 + 4];   // reflect(W)=W−2
    xn[0] = left; xn[1] = v.x; xn[2] = v.y; xn[3] = v.z; xn[4] = v.w; xn[5] = right;
}

__global__ __launch_bounds__(256)
void pm_kernel(const float* __restrict__ x, float* __restrict__ out) {
    const int H = HH, W = WW;
    const int r0 = blockIdx.x * RR;       // first output row of this tile
    const int b  = blockIdx.y;
    const float* xb = x + (size_t)b * H * W;
    float*       ob = out + (size_t)b * H * W;
    const int j0   = threadIdx.x << 2;    // 4 pixels/thread, block spans the row
    const int lane = threadIdx.x & 63;
    const float c = 0.70710678118654752f;

    // ---- prologue: row above (reflected) + first tile row ----
    float xm[6], xr[6];
    {
        const int pm = (r0 >= 1) ? r0 - 1 : 1;     // reflect(r0-1)
        load_row6(xb + (size_t)pm * W, j0, lane, xm);
        load_row6(xb + (size_t)r0 * W, j0, lane, xr);
    }

    // (g,h) for row r0: gw covers cols j0-1..j0+3, hc covers j0..j0+3
    float gw[5], hc[4], hprev[4];
#pragma unroll
    for (int t = 0; t < 5; ++t) {
        float g, h;
        gh_eval(xr[t], xr[t + 1], xm[t], g, h);
        gw[t] = g;
        if (t >= 1) hc[t - 1] = h;
    }
    if (j0 == 0) gw[0] = gw[2];           // jm(0)=1 -> g(i,1)

    // ---- body: rows r0 .. r0+RR-2 always have a next row in-bounds ----
#pragma unroll
    for (int k = 0; k < RR - 1; ++k) {
        const int r = r0 + k;
        float xn[6];
        load_row6(xb + (size_t)(r + 1) * W, j0, lane, xn);

        float gw2[5], hn[4];
#pragma unroll
        for (int t = 0; t < 5; ++t) {
            float g, h;
            gh_eval(xn[t], xn[t + 1], xr[t], g, h);
            gw2[t] = g;
            if (t >= 1) hn[t - 1] = h;
        }
        if (j0 == 0) gw2[0] = gw2[2];

        store_nt4(ob + (size_t)r * W + j0,
                  c * ((gw[1] - gw[0]) + (hc[0] - hn[0])),
                  c * ((gw[2] - gw[1]) + (hc[1] - hn[1])),
                  c * ((gw[3] - gw[2]) + (hc[2] - hn[2])),
                  c * ((gw[4] - gw[3]) + (hc[3] - hn[3])));

        // shift state down one row
#pragma unroll
        for (int t = 0; t < 6; ++t) xr[t] = xn[t];
#pragma unroll
        for (int t = 0; t < 5; ++t) gw[t] = gw2[t];
#pragma unroll
        for (int t = 0; t < 4; ++t) { hprev[t] = hc[t]; hc[t] = hn[t]; }
    }

    // ---- epilogue row rL = r0+RR-1 ----
    {
        const int rL = r0 + RR - 1;
        float hP[4];
        if (rL + 1 < H) {                  // interior tile: load the halo row
            float xn[6];
            load_row6(xb + (size_t)(rL + 1) * W, j0, lane, xn);
#pragma unroll
            for (int t = 1; t < 5; ++t) {  // only h needed (cols j0..j0+3)
                float g, h;
                gh_eval(xn[t], xn[t + 1], xr[t], g, h);
                hP[t - 1] = h;
            }
        } else {                           // rL = H-1: ip reflects to H-2
            hP[0] = hprev[0]; hP[1] = hprev[1];
            hP[2] = hprev[2]; hP[3] = hprev[3];
        }
        store_nt4(ob + (size_t)rL * W + j0,
                  c * ((gw[1] - gw[0]) + (hc[0] - hP[0])),
                  c * ((gw[2] - gw[1]) + (hc[1] - hP[1])),
                  c * ((gw[3] - gw[2]) + (hc[2] - hP[2])),
                  c * ((gw[4] - gw[3]) + (hc[3] - hP[3])));
    }
}

extern "C" void kernel_launch(void* const* d_in, const int* in_sizes, int n_in,
                              void* d_out, int out_size, void* d_ws, size_t ws_size,
                              hipStream_t stream) {
    const float* x = (const float*)d_in[0];
    float* out = (float*)d_out;
    const int total = in_sizes[0];
    const int B = total / (HH * WW);       // 16
    dim3 grid(HH / RR, B);                 // 8-row tile per block
    pm_kernel<<<grid, 256, 0, stream>>>(x, out);
}